// Round 4
// baseline (672.257 us; speedup 1.0000x reference)
//
#include <hip/hip_runtime.h>
#include <cstdint>
#include <cstddef>

#define HD   1024
#define SEQL 200
#define MEMN 50
#define RTOT 51200   // 256 * 200
#define KP   128
#define PADK 136     // KP + 8 bf16 pad -> LDS row stride 272B (2-way, free)

typedef float  f4    __attribute__((ext_vector_type(4)));
typedef float  f32x4 __attribute__((ext_vector_type(4)));
typedef short  s16x8 __attribute__((ext_vector_type(8)));
typedef unsigned short u16;
typedef unsigned short u16x4 __attribute__((ext_vector_type(4)));

__device__ __forceinline__ u16 f2bf(float f) {
    unsigned u = __builtin_bit_cast(unsigned, f);
    u += 0x7FFFu + ((u >> 16) & 1u);          // RNE
    return (u16)(u >> 16);
}
__device__ __forceinline__ float bf2f(u16 h) {
    unsigned u = ((unsigned)h) << 16;
    return __builtin_bit_cast(float, u);
}

#define GLOAD_LDS16(g, l) __builtin_amdgcn_global_load_lds( \
    (const __attribute__((address_space(1))) unsigned int*)(g), \
    (__attribute__((address_space(3))) unsigned int*)(l), 16, 0, 0)

#define WAITV4 asm volatile("s_waitcnt vmcnt(4)" ::: "memory")
#define WAITV0 asm volatile("s_waitcnt vmcnt(0)" ::: "memory")
#define LGKM0  asm volatile("s_waitcnt lgkmcnt(0)" ::: "memory")
#define SCHB   __builtin_amdgcn_sched_barrier(0)

// ---------------------------------------------------------------------------
// K0a: gate_w f32 -> bf16 (layout preserved: [o][2048], K-contiguous)
// ---------------------------------------------------------------------------
__global__ __launch_bounds__(256) void k_cvt_w(const float* __restrict__ gw,
                                               u16* __restrict__ gwB)
{
    const size_t i = ((size_t)blockIdx.x * 256 + threadIdx.x) * 8;
    f4 v0 = *(const f4*)&gw[i];
    f4 v1 = *(const f4*)&gw[i + 4];
    u16x4 b0 = { f2bf(v0.x), f2bf(v0.y), f2bf(v0.z), f2bf(v0.w) };
    u16x4 b1 = { f2bf(v1.x), f2bf(v1.y), f2bf(v1.z), f2bf(v1.w) };
    *(u16x4*)&gwB[i]     = b0;
    *(u16x4*)&gwB[i + 4] = b1;
}

// ---------------------------------------------------------------------------
// K0b: spatial memory -> {memHi, memLo} [64][1024] bf16 (rows 50..63 zero)
//      and memT [1024][64] bf16 (hi only, transposed, zero-padded).
// ---------------------------------------------------------------------------
__global__ __launch_bounds__(256) void k_prep_mem(const float* __restrict__ sm,
                                                  u16* __restrict__ memHi,
                                                  u16* __restrict__ memLo,
                                                  u16* __restrict__ memT)
{
    const int idx = blockIdx.x * 256 + threadIdx.x;   // 16384 total
    const int m  = idx >> 8;
    const int h0 = (idx & 255) * 4;
    f4 v = {0.f, 0.f, 0.f, 0.f};
    if (m < MEMN) v = *(const f4*)&sm[(size_t)m * HD + h0];
    u16x4 hi = { f2bf(v.x), f2bf(v.y), f2bf(v.z), f2bf(v.w) };
    f4 hv = { bf2f(hi.x), bf2f(hi.y), bf2f(hi.z), bf2f(hi.w) };
    f4 lv = v - hv;
    u16x4 lo = { f2bf(lv.x), f2bf(lv.y), f2bf(lv.z), f2bf(lv.w) };
    *(u16x4*)&memHi[(size_t)m * HD + h0] = hi;
    *(u16x4*)&memLo[(size_t)m * HD + h0] = lo;
    memT[(size_t)(h0 + 0) * 64 + m] = hi.x;
    memT[(size_t)(h0 + 1) * 64 + m] = hi.y;
    memT[(size_t)(h0 + 2) * 64 + m] = hi.z;
    memT[(size_t)(h0 + 3) * 64 + m] = hi.w;
}

// ---------------------------------------------------------------------------
// K1: feats = x + pos (store bf16); sim via bf16x2-split MFMA; softmax;
//     mem_read via MFMA (store bf16). 64 rows/block, 4 waves.
// ---------------------------------------------------------------------------
__global__ __launch_bounds__(256) void k_pre(
    const float* __restrict__ x, const float* __restrict__ pos,
    const u16* __restrict__ memHi, const u16* __restrict__ memLo,
    const u16* __restrict__ memT,
    u16* __restrict__ featsB, u16* __restrict__ memrB)
{
    __shared__ u16 fHi[64 * PADK];
    __shared__ u16 fLo[64 * PADK];
    __shared__ u16 wB[64 * 72];      // softmax weights bf16, row stride 144B

    const int tid  = threadIdx.x;
    const int r0   = blockIdx.x * 64;
    const int lane = tid & 63, w = tid >> 6;
    const int fr   = lane & 15;           // MFMA frag row/col within tile
    const int fk   = (lane >> 4) * 8;     // MFMA frag k offset
    const int jr   = (lane >> 4) * 4;     // C-frag row base

    const int srow = tid >> 2;            // staging row 0..63 (== wave's rows)
    const int scol = (tid & 3) * 4;
    const int prow = (r0 + srow) % SEQL;

    f32x4 acc[4] = {};                    // sim[16 rows][m = n*16 + fr]

    for (int kp = 0; kp < HD; kp += KP) {
        // ---- stage feats hi/lo into LDS, emit bf16 feats to global ----
        #pragma unroll
        for (int i = 0; i < 8; ++i) {
            const int c = scol + i * 16;
            f4 xv = *(const f4*)&x[(size_t)(r0 + srow) * HD + kp + c];
            f4 pv = *(const f4*)&pos[(size_t)prow * HD + kp + c];
            f4 fv = xv + pv;
            u16x4 hi = { f2bf(fv.x), f2bf(fv.y), f2bf(fv.z), f2bf(fv.w) };
            f4 hv = { bf2f(hi.x), bf2f(hi.y), bf2f(hi.z), bf2f(hi.w) };
            f4 lv = fv - hv;
            u16x4 lo = { f2bf(lv.x), f2bf(lv.y), f2bf(lv.z), f2bf(lv.w) };
            *(u16x4*)&fHi[srow * PADK + c] = hi;
            *(u16x4*)&fLo[srow * PADK + c] = lo;
            *(u16x4*)&featsB[(size_t)(r0 + srow) * HD + kp + c] = hi;
        }
        __syncthreads();

        // ---- sim MFMA: 3 split-passes, B-frags straight from L2 ----
        #pragma unroll
        for (int ks = 0; ks < KP / 32; ++ks) {
            const int kb = ks * 32 + fk;
            s16x8 aH = *(const s16x8*)&fHi[(16 * w + fr) * PADK + kb];
            s16x8 aL = *(const s16x8*)&fLo[(16 * w + fr) * PADK + kb];
            #pragma unroll
            for (int n = 0; n < 4; ++n) {
                const size_t mb = (size_t)(n * 16 + fr) * HD + kp + kb;
                s16x8 bH = *(const s16x8*)&memHi[mb];
                s16x8 bL = *(const s16x8*)&memLo[mb];
                acc[n] = __builtin_amdgcn_mfma_f32_16x16x32_bf16(aH, bH, acc[n], 0, 0, 0);
                acc[n] = __builtin_amdgcn_mfma_f32_16x16x32_bf16(aH, bL, acc[n], 0, 0, 0);
                acc[n] = __builtin_amdgcn_mfma_f32_16x16x32_bf16(aL, bH, acc[n], 0, 0, 0);
            }
        }
        __syncthreads();
    }

    // ---- softmax over m (50) in f32 ----
    #pragma unroll
    for (int j = 0; j < 4; ++j) {
        float v[4];
        float mx = -1e30f;
        #pragma unroll
        for (int n = 0; n < 4; ++n) {
            v[n] = acc[n][j];
            const int m = n * 16 + fr;
            if (m < MEMN) mx = fmaxf(mx, v[n]);
        }
        #pragma unroll
        for (int d = 1; d < 16; d <<= 1) mx = fmaxf(mx, __shfl_xor(mx, d));
        float e[4], s = 0.f;
        #pragma unroll
        for (int n = 0; n < 4; ++n) {
            const int m = n * 16 + fr;
            e[n] = (m < MEMN) ? __expf(v[n] - mx) : 0.f;
            s += e[n];
        }
        #pragma unroll
        for (int d = 1; d < 16; d <<= 1) s += __shfl_xor(s, d);
        const float inv = 1.f / s;
        const int rloc = 16 * w + jr + j;
        #pragma unroll
        for (int n = 0; n < 4; ++n)
            wB[rloc * 72 + n * 16 + fr] = f2bf(e[n] * inv);   // 0 for m>=50
    }

    // ---- mem_read = w @ mem via MFMA (K = 64, zero-padded) ----
    s16x8 aW[2];
    #pragma unroll
    for (int ks = 0; ks < 2; ++ks)
        aW[ks] = *(const s16x8*)&wB[(16 * w + fr) * 72 + ks * 32 + fk];

    for (int c0 = 0; c0 < HD; c0 += 128) {
        f32x4 a2[8] = {};
        #pragma unroll
        for (int ks = 0; ks < 2; ++ks) {
            #pragma unroll
            for (int nt = 0; nt < 8; ++nt) {
                const int h = c0 + nt * 16 + fr;
                s16x8 bT = *(const s16x8*)&memT[(size_t)h * 64 + ks * 32 + fk];
                a2[nt] = __builtin_amdgcn_mfma_f32_16x16x32_bf16(aW[ks], bT, a2[nt], 0, 0, 0);
            }
        }
        #pragma unroll
        for (int nt = 0; nt < 8; ++nt) {
            const int h = c0 + nt * 16 + fr;
            #pragma unroll
            for (int j = 0; j < 4; ++j) {
                const int r = r0 + 16 * w + jr + j;
                memrB[(size_t)r * HD + h] = f2bf(a2[nt][j]);
            }
        }
    }
}

// ---------------------------------------------------------------------------
// K2: gate GEMM (M=51200, N=1024, K=2048 concat) + sigmoid + residual out.
//     m201 structure: BM=BN=256, BK=64, 8 waves (2Mx4N), per-wave 128x64,
//     2-dbuf LDS (128 KB), 4 quadrant-phases per K-tile, counted vmcnt(4),
//     XOR-swizzled LDS via pre-swizzled global source.
// ---------------------------------------------------------------------------
__global__ __launch_bounds__(512, 2) void k_gate_out(
    const u16* __restrict__ featsB, const u16* __restrict__ memrB,
    const u16* __restrict__ gwB, const float* __restrict__ gb,
    float* __restrict__ out)
{
    __shared__ u16 As[2][256 * 64];   // 64 KB
    __shared__ u16 Bs[2][256 * 64];   // 64 KB

    const int tid = threadIdx.x;
    int bid = blockIdx.x;
    bid = (bid & 7) * 100 + (bid >> 3);        // XCD swizzle (800 % 8 == 0)
    const int mt = bid >> 2, nt = bid & 3;     // 200 x 4 tiles
    const int row0 = mt * 256, col0 = nt * 256;
    const int lane = tid & 63, w = tid >> 6;   // 8 waves
    const int wm = w >> 2, wn = w & 3;         // 2M x 4N
    const int fr = lane & 15, sg = lane >> 4;
    const int sA = sg ^ (fr & 7);              // swizzled 16B slot (read side)

    // staging lane geometry: per gload instr 8 rows x 128B, linear LDS dest
    const int lr = lane >> 3, lp = lane & 7;
    const int cs = (lp ^ lr) * 8;              // pre-swizzled source col (elems)

    f32x4 acc[8][4] = {};

    // stage half-pair h of K-tile kt: h=0 -> A rows 0..127 + B cols 0..127,
    // h=1 -> A rows 128..255 + B cols 128..255.  4 gloads/thread.
    auto stageAB = [&](int buf, int kt, int h) {
        const u16* Asrc = (kt < 16) ? featsB : memrB;
        const int k0 = (kt & 15) * 64;
        #pragma unroll
        for (int j = 0; j < 2; ++j) {
            const int rb = h * 128 + w * 16 + j * 8;   // wave-uniform base row
            const int r  = rb + lr;
            GLOAD_LDS16(Asrc + (size_t)(row0 + r) * HD + k0 + cs,
                        &As[buf][rb * 64]);
        }
        #pragma unroll
        for (int j = 0; j < 2; ++j) {
            const int rb = h * 128 + w * 16 + j * 8;
            const int r  = rb + lr;
            GLOAD_LDS16(gwB + (size_t)(col0 + r) * 2048 + kt * 64 + cs,
                        &Bs[buf][rb * 64]);
        }
    };

    s16x8 aF[4][2], bF[2][2];
    auto readA = [&](int buf, int mh) {
        #pragma unroll
        for (int i = 0; i < 4; ++i) {
            const int r = wm * 128 + (mh * 4 + i) * 16 + fr;
            aF[i][0] = *(const s16x8*)&As[buf][r * 64 + sA * 8];
            aF[i][1] = *(const s16x8*)&As[buf][r * 64 + (sA ^ 4) * 8];
        }
    };
    auto readB = [&](int buf, int nh) {
        #pragma unroll
        for (int i = 0; i < 2; ++i) {
            const int c = wn * 64 + (nh * 2 + i) * 16 + fr;
            bF[i][0] = *(const s16x8*)&Bs[buf][c * 64 + sA * 8];
            bF[i][1] = *(const s16x8*)&Bs[buf][c * 64 + (sA ^ 4) * 8];
        }
    };
    auto mfma16 = [&](int mh, int nh) {
        __builtin_amdgcn_s_setprio(1);
        #pragma unroll
        for (int ks = 0; ks < 2; ++ks)
            #pragma unroll
            for (int i = 0; i < 4; ++i)
                #pragma unroll
                for (int jn = 0; jn < 2; ++jn)
                    acc[mh * 4 + i][nh * 2 + jn] =
                        __builtin_amdgcn_mfma_f32_16x16x32_bf16(
                            aF[i][ks], bF[jn][ks],
                            acc[mh * 4 + i][nh * 2 + jn], 0, 0, 0);
        __builtin_amdgcn_s_setprio(0);
    };

    // prologue: K-tile 0 fully staged into buf 0
    stageAB(0, 0, 0);
    stageAB(0, 0, 1);

    for (int T = 0; T < 32; ++T) {
        const int buf = T & 1;
        // ---- q0: (mh0, nh0) ----
        if (T < 31) { stageAB(buf ^ 1, T + 1, 0); WAITV4; }
        else        { WAITV0; }
        __builtin_amdgcn_s_barrier();          // K-tile T collectively visible
        readA(buf, 0); readB(buf, 0);
        LGKM0; SCHB;
        mfma16(0, 0);
        __builtin_amdgcn_s_barrier();
        // ---- q1: (mh1, nh0) ----
        if (T < 31) stageAB(buf ^ 1, T + 1, 1);
        __builtin_amdgcn_s_barrier();
        readA(buf, 1);
        LGKM0; SCHB;
        mfma16(1, 0);
        __builtin_amdgcn_s_barrier();
        // ---- q2: (mh1, nh1) ----
        readB(buf, 1);
        LGKM0; SCHB;
        mfma16(1, 1);
        __builtin_amdgcn_s_barrier();
        // ---- q3: (mh0, nh1) ----
        readA(buf, 0);
        LGKM0; SCHB;
        mfma16(0, 1);
        __builtin_amdgcn_s_barrier();          // all reads of buf done
    }

    // epilogue: out = feats + sigmoid(acc + b) * mem_read
    #pragma unroll
    for (int m = 0; m < 8; ++m) {
        #pragma unroll
        for (int n = 0; n < 4; ++n) {
            const int crow = row0 + wm * 128 + m * 16 + sg * 4;
            const int ccol = col0 + wn * 64 + n * 16 + fr;
            const float bias = gb[ccol];
            #pragma unroll
            for (int j = 0; j < 4; ++j) {
                const size_t idx = (size_t)(crow + j) * HD + ccol;
                const float fe = bf2f(featsB[idx]);
                const float mr = bf2f(memrB[idx]);
                const float pre = acc[m][n][j] + bias;
                const float g = 1.0f / (1.0f + __expf(-pre));
                out[idx] = fe + g * mr;
            }
        }
    }
}

// ---------------------------------------------------------------------------
extern "C" void kernel_launch(void* const* d_in, const int* in_sizes, int n_in,
                              void* d_out, int out_size, void* d_ws, size_t ws_size,
                              hipStream_t stream)
{
    const float* x   = (const float*)d_in[0];
    const float* sm  = (const float*)d_in[1];
    const float* pos = (const float*)d_in[2];
    const float* gw  = (const float*)d_in[3];
    const float* gb  = (const float*)d_in[4];
    float* out = (float*)d_out;

    u16* featsB = (u16*)d_ws;                          // 51200*1024
    u16* memrB  = featsB + (size_t)RTOT * HD;          // 51200*1024
    u16* gwB    = memrB + (size_t)RTOT * HD;           // 1024*2048
    u16* memHi  = gwB + (size_t)HD * 2048;             // 64*1024
    u16* memLo  = memHi + 64 * HD;                     // 64*1024
    u16* memT   = memLo + 64 * HD;                     // 1024*64

    k_cvt_w<<<dim3(1024), dim3(256), 0, stream>>>(gw, gwB);
    k_prep_mem<<<dim3(64), dim3(256), 0, stream>>>(sm, memHi, memLo, memT);
    k_pre<<<dim3(RTOT / 64), dim3(256), 0, stream>>>(x, pos, memHi, memLo, memT,
                                                     featsB, memrB);
    k_gate_out<<<dim3(800), dim3(512), 0, stream>>>(featsB, memrB, gwB, gb, out);
}

// Round 5
// 659.821 us; speedup vs baseline: 1.0188x; 1.0188x over previous
//
#include <hip/hip_runtime.h>
#include <cstdint>
#include <cstddef>

#define HD   1024
#define SEQL 200
#define MEMN 50
#define RTOT 51200   // 256 * 200
#define KP   128
#define PADK 136     // KP + 8 bf16 pad -> LDS row stride 272B (2-way, free)

typedef float  f4    __attribute__((ext_vector_type(4)));
typedef float  f32x4 __attribute__((ext_vector_type(4)));
typedef short  s16x8 __attribute__((ext_vector_type(8)));
typedef unsigned short u16;
typedef unsigned short u16x4 __attribute__((ext_vector_type(4)));

__device__ __forceinline__ u16 f2bf(float f) {
    unsigned u = __builtin_bit_cast(unsigned, f);
    u += 0x7FFFu + ((u >> 16) & 1u);          // RNE
    return (u16)(u >> 16);
}
__device__ __forceinline__ float bf2f(u16 h) {
    unsigned u = ((unsigned)h) << 16;
    return __builtin_bit_cast(float, u);
}

#define GLOAD_LDS16(g, l) __builtin_amdgcn_global_load_lds( \
    (const __attribute__((address_space(1))) unsigned int*)(g), \
    (__attribute__((address_space(3))) unsigned int*)(l), 16, 0, 0)

#define WAITV8 asm volatile("s_waitcnt vmcnt(8)" ::: "memory")
#define WAITV4 asm volatile("s_waitcnt vmcnt(4)" ::: "memory")
#define WAITV0 asm volatile("s_waitcnt vmcnt(0)" ::: "memory")
#define LGKMFENCE asm volatile("s_waitcnt lgkmcnt(0)" ::: "memory")
#define SCHB   __builtin_amdgcn_sched_barrier(0)

// ---------------------------------------------------------------------------
// K0a: gate_w f32 -> bf16 (layout preserved: [o][2048], K-contiguous)
// ---------------------------------------------------------------------------
__global__ __launch_bounds__(256) void k_cvt_w(const float* __restrict__ gw,
                                               u16* __restrict__ gwB)
{
    const size_t i = ((size_t)blockIdx.x * 256 + threadIdx.x) * 8;
    f4 v0 = *(const f4*)&gw[i];
    f4 v1 = *(const f4*)&gw[i + 4];
    u16x4 b0 = { f2bf(v0.x), f2bf(v0.y), f2bf(v0.z), f2bf(v0.w) };
    u16x4 b1 = { f2bf(v1.x), f2bf(v1.y), f2bf(v1.z), f2bf(v1.w) };
    *(u16x4*)&gwB[i]     = b0;
    *(u16x4*)&gwB[i + 4] = b1;
}

// ---------------------------------------------------------------------------
// K0b: spatial memory -> {memHi, memLo} [64][1024] bf16 (rows 50..63 zero)
//      and memT [1024][64] bf16 (hi only, transposed, zero-padded).
// ---------------------------------------------------------------------------
__global__ __launch_bounds__(256) void k_prep_mem(const float* __restrict__ sm,
                                                  u16* __restrict__ memHi,
                                                  u16* __restrict__ memLo,
                                                  u16* __restrict__ memT)
{
    const int idx = blockIdx.x * 256 + threadIdx.x;   // 16384 total
    const int m  = idx >> 8;
    const int h0 = (idx & 255) * 4;
    f4 v = {0.f, 0.f, 0.f, 0.f};
    if (m < MEMN) v = *(const f4*)&sm[(size_t)m * HD + h0];
    u16x4 hi = { f2bf(v.x), f2bf(v.y), f2bf(v.z), f2bf(v.w) };
    f4 hv = { bf2f(hi.x), bf2f(hi.y), bf2f(hi.z), bf2f(hi.w) };
    f4 lv = v - hv;
    u16x4 lo = { f2bf(lv.x), f2bf(lv.y), f2bf(lv.z), f2bf(lv.w) };
    *(u16x4*)&memHi[(size_t)m * HD + h0] = hi;
    *(u16x4*)&memLo[(size_t)m * HD + h0] = lo;
    memT[(size_t)(h0 + 0) * 64 + m] = hi.x;
    memT[(size_t)(h0 + 1) * 64 + m] = hi.y;
    memT[(size_t)(h0 + 2) * 64 + m] = hi.z;
    memT[(size_t)(h0 + 3) * 64 + m] = hi.w;
}

// ---------------------------------------------------------------------------
// K1: feats = x + pos (store bf16); sim via bf16x2-split MFMA; softmax;
//     mem_read via MFMA (store bf16). 64 rows/block, 4 waves.
//     BARRIER-FREE: every LDS row is written and read by the same wave
//     (wave w owns rows 16w..16w+15), so only wave-local lgkmcnt fences.
// ---------------------------------------------------------------------------
__global__ __launch_bounds__(256) void k_pre(
    const float* __restrict__ x, const float* __restrict__ pos,
    const u16* __restrict__ memHi, const u16* __restrict__ memLo,
    const u16* __restrict__ memT,
    u16* __restrict__ featsB, u16* __restrict__ memrB)
{
    __shared__ u16 fHi[64 * PADK];
    __shared__ u16 fLo[64 * PADK];
    __shared__ u16 wB[64 * 72];      // softmax weights bf16, row stride 144B

    const int tid  = threadIdx.x;
    const int r0   = blockIdx.x * 64;
    const int lane = tid & 63, w = tid >> 6;
    const int fr   = lane & 15;           // MFMA frag row/col within tile
    const int fk   = (lane >> 4) * 8;     // MFMA frag k offset
    const int jr   = (lane >> 4) * 4;     // C-frag row base

    const int srow = tid >> 2;            // staging row 0..63 (== wave's rows)
    const int scol = (tid & 3) * 4;
    const int prow = (r0 + srow) % SEQL;

    f32x4 acc[4] = {};                    // sim[16 rows][m = n*16 + fr]

    for (int kp = 0; kp < HD; kp += KP) {
        // ---- stage feats hi/lo into LDS, emit bf16 feats to global ----
        #pragma unroll
        for (int i = 0; i < 8; ++i) {
            const int c = scol + i * 16;
            f4 xv = *(const f4*)&x[(size_t)(r0 + srow) * HD + kp + c];
            f4 pv = *(const f4*)&pos[(size_t)prow * HD + kp + c];
            f4 fv = xv + pv;
            u16x4 hi = { f2bf(fv.x), f2bf(fv.y), f2bf(fv.z), f2bf(fv.w) };
            f4 hv = { bf2f(hi.x), bf2f(hi.y), bf2f(hi.z), bf2f(hi.w) };
            f4 lv = fv - hv;
            u16x4 lo = { f2bf(lv.x), f2bf(lv.y), f2bf(lv.z), f2bf(lv.w) };
            *(u16x4*)&fHi[srow * PADK + c] = hi;
            *(u16x4*)&fLo[srow * PADK + c] = lo;
            *(u16x4*)&featsB[(size_t)(r0 + srow) * HD + kp + c] = hi;
        }
        LGKMFENCE;   // wave-local: staging writes visible to this wave's reads

        // ---- sim MFMA: 3 split-passes, B-frags straight from L2 ----
        #pragma unroll
        for (int ks = 0; ks < KP / 32; ++ks) {
            const int kb = ks * 32 + fk;
            s16x8 aH = *(const s16x8*)&fHi[(16 * w + fr) * PADK + kb];
            s16x8 aL = *(const s16x8*)&fLo[(16 * w + fr) * PADK + kb];
            #pragma unroll
            for (int n = 0; n < 4; ++n) {
                const size_t mb = (size_t)(n * 16 + fr) * HD + kp + kb;
                s16x8 bH = *(const s16x8*)&memHi[mb];
                s16x8 bL = *(const s16x8*)&memLo[mb];
                acc[n] = __builtin_amdgcn_mfma_f32_16x16x32_bf16(aH, bH, acc[n], 0, 0, 0);
                acc[n] = __builtin_amdgcn_mfma_f32_16x16x32_bf16(aH, bL, acc[n], 0, 0, 0);
                acc[n] = __builtin_amdgcn_mfma_f32_16x16x32_bf16(aL, bH, acc[n], 0, 0, 0);
            }
        }
        LGKMFENCE;   // reads of this panel done before next panel's writes
    }

    // ---- softmax over m (50) in f32 ----
    #pragma unroll
    for (int j = 0; j < 4; ++j) {
        float v[4];
        float mx = -1e30f;
        #pragma unroll
        for (int n = 0; n < 4; ++n) {
            v[n] = acc[n][j];
            const int m = n * 16 + fr;
            if (m < MEMN) mx = fmaxf(mx, v[n]);
        }
        #pragma unroll
        for (int d = 1; d < 16; d <<= 1) mx = fmaxf(mx, __shfl_xor(mx, d));
        float e[4], s = 0.f;
        #pragma unroll
        for (int n = 0; n < 4; ++n) {
            const int m = n * 16 + fr;
            e[n] = (m < MEMN) ? __expf(v[n] - mx) : 0.f;
            s += e[n];
        }
        #pragma unroll
        for (int d = 1; d < 16; d <<= 1) s += __shfl_xor(s, d);
        const float inv = 1.f / s;
        const int rloc = 16 * w + jr + j;
        #pragma unroll
        for (int n = 0; n < 4; ++n)
            wB[rloc * 72 + n * 16 + fr] = f2bf(e[n] * inv);   // 0 for m>=50
    }
    LGKMFENCE;       // wave-local: wB writes visible to this wave's reads

    // ---- mem_read = w @ mem via MFMA (K = 64, zero-padded) ----
    s16x8 aW[2];
    #pragma unroll
    for (int ks = 0; ks < 2; ++ks)
        aW[ks] = *(const s16x8*)&wB[(16 * w + fr) * 72 + ks * 32 + fk];

    for (int c0 = 0; c0 < HD; c0 += 128) {
        f32x4 a2[8] = {};
        #pragma unroll
        for (int ks = 0; ks < 2; ++ks) {
            #pragma unroll
            for (int nt = 0; nt < 8; ++nt) {
                const int h = c0 + nt * 16 + fr;
                s16x8 bT = *(const s16x8*)&memT[(size_t)h * 64 + ks * 32 + fk];
                a2[nt] = __builtin_amdgcn_mfma_f32_16x16x32_bf16(aW[ks], bT, a2[nt], 0, 0, 0);
            }
        }
        #pragma unroll
        for (int nt = 0; nt < 8; ++nt) {
            const int h = c0 + nt * 16 + fr;
            #pragma unroll
            for (int j = 0; j < 4; ++j) {
                const int r = r0 + 16 * w + jr + j;
                memrB[(size_t)r * HD + h] = f2bf(a2[nt][j]);
            }
        }
    }
}

// ---------------------------------------------------------------------------
// K2: gate GEMM (M=51200, N=1024, K=2048 concat) + sigmoid + residual out.
//     Round-2 skeleton: 128x128 tile, BK=32, 4 waves (2x2), 256 threads.
//     Upgrades: 3 LDS buffers / prefetch distance 2 / vmcnt(8) (wait covers
//     loads issued ~2 iters (~1000cy) ago > HBM latency), 2-way LDS swizzle
//     (pre-swizzled source + same involution on ds_read -> ~0 conflicts),
//     setprio around MFMA. 48 KB LDS -> 3 blocks/CU.
// ---------------------------------------------------------------------------
__global__ __launch_bounds__(256) void k_gate_out(
    const u16* __restrict__ featsB, const u16* __restrict__ memrB,
    const u16* __restrict__ gwB, const float* __restrict__ gb,
    float* __restrict__ out)
{
    __shared__ u16 As[3][128 * 32];   // 24 KB
    __shared__ u16 Bs[3][128 * 32];   // 24 KB

    const int tid = threadIdx.x;
    int bid = blockIdx.x;
    bid = (bid & 7) * 400 + (bid >> 3);      // XCD swizzle (3200 % 8 == 0)
    const int mt = bid >> 3, nt = bid & 7;
    const int row0 = mt * 128, col0 = nt * 128;
    const int lane = tid & 63, w = tid >> 6;
    const int wr = w >> 1, wc = w & 1;
    const int fr = lane & 15, sg = lane >> 4;
    const int sl = sg ^ ((fr >> 1) & 3);     // swizzled 16B slot (read side)

    // staging geometry: per instr per wave: 16 rows x 64B, linear LDS dest
    const int lr = lane >> 2;                // row within 16-row chunk
    const int lp = lane & 3;                 // phys 16B slot

    f32x4 acc[4][4] = {};

    auto stage = [&](int buf, int kt) {
        const u16* Asrc = (kt < 32) ? featsB : memrB;
        const int k0 = (kt & 31) * 32;
        #pragma unroll
        for (int i = 0; i < 2; ++i) {
            const int rb = w * 32 + i * 16;            // wave-uniform base row
            const int r  = rb + lr;
            const int c  = (lp ^ ((r >> 1) & 3)) * 8;  // pre-swizzled source
            GLOAD_LDS16(Asrc + (size_t)(row0 + r) * HD + k0 + c,
                        &As[buf][rb * 32]);
            GLOAD_LDS16(gwB + (size_t)(col0 + r) * 2048 + kt * 32 + c,
                        &Bs[buf][rb * 32]);
        }
    };

    stage(0, 0); stage(1, 1);                // prologue: 2 tiles deep

    for (int kt = 0; kt < 64; ++kt) {
        const int buf = kt % 3;
        if (kt < 62) {                        // re-stage legal: end-barrier of
            stage((kt + 2) % 3, kt + 2);      // iter kt-1 freed this buffer
            WAITV8;                           // wait for tile kt only
        } else if (kt == 62) { WAITV4; }
        else                 { WAITV0; }
        __builtin_amdgcn_s_barrier();         // tile kt collectively visible
        SCHB;

        s16x8 aF[4], bF[4];
        #pragma unroll
        for (int m = 0; m < 4; ++m)
            aF[m] = *(const s16x8*)&As[buf][(wr * 64 + m * 16 + fr) * 32 + sl * 8];
        #pragma unroll
        for (int n = 0; n < 4; ++n)
            bF[n] = *(const s16x8*)&Bs[buf][(wc * 64 + n * 16 + fr) * 32 + sl * 8];

        __builtin_amdgcn_s_setprio(1);
        #pragma unroll
        for (int m = 0; m < 4; ++m)
            #pragma unroll
            for (int n = 0; n < 4; ++n)
                acc[m][n] = __builtin_amdgcn_mfma_f32_16x16x32_bf16(
                    aF[m], bF[n], acc[m][n], 0, 0, 0);
        __builtin_amdgcn_s_setprio(0);

        SCHB;
        __builtin_amdgcn_s_barrier();         // all waves done reading buf
    }

    // epilogue: out = feats + sigmoid(acc + b) * mem_read
    #pragma unroll
    for (int m = 0; m < 4; ++m) {
        #pragma unroll
        for (int n = 0; n < 4; ++n) {
            const int crow = row0 + wr * 64 + m * 16 + sg * 4;
            const int ccol = col0 + wc * 64 + n * 16 + fr;
            const float bias = gb[ccol];
            #pragma unroll
            for (int j = 0; j < 4; ++j) {
                const size_t idx = (size_t)(crow + j) * HD + ccol;
                const float fe = bf2f(featsB[idx]);
                const float mr = bf2f(memrB[idx]);
                const float pre = acc[m][n][j] + bias;
                const float g = 1.0f / (1.0f + __expf(-pre));
                out[idx] = fe + g * mr;
            }
        }
    }
}

// ---------------------------------------------------------------------------
extern "C" void kernel_launch(void* const* d_in, const int* in_sizes, int n_in,
                              void* d_out, int out_size, void* d_ws, size_t ws_size,
                              hipStream_t stream)
{
    const float* x   = (const float*)d_in[0];
    const float* sm  = (const float*)d_in[1];
    const float* pos = (const float*)d_in[2];
    const float* gw  = (const float*)d_in[3];
    const float* gb  = (const float*)d_in[4];
    float* out = (float*)d_out;

    u16* featsB = (u16*)d_ws;                          // 51200*1024
    u16* memrB  = featsB + (size_t)RTOT * HD;          // 51200*1024
    u16* gwB    = memrB + (size_t)RTOT * HD;           // 1024*2048
    u16* memHi  = gwB + (size_t)HD * 2048;             // 64*1024
    u16* memLo  = memHi + 64 * HD;                     // 64*1024
    u16* memT   = memLo + 64 * HD;                     // 1024*64

    k_cvt_w<<<dim3(1024), dim3(256), 0, stream>>>(gw, gwB);
    k_prep_mem<<<dim3(64), dim3(256), 0, stream>>>(sm, memHi, memLo, memT);
    k_pre<<<dim3(RTOT / 64), dim3(256), 0, stream>>>(x, pos, memHi, memLo, memT,
                                                     featsB, memrB);
    k_gate_out<<<dim3(3200), dim3(256), 0, stream>>>(featsB, memrB, gwB, gb, out);
}

// Round 6
// 614.182 us; speedup vs baseline: 1.0946x; 1.0743x over previous
//
#include <hip/hip_runtime.h>
#include <cstdint>
#include <cstddef>

#define HD   1024
#define SEQL 200
#define MEMN 50
#define RTOT 51200   // 256 * 200
#define KP   128
#define PADK 136     // KP + 8 bf16 pad -> LDS row stride 272B (2-way, free)

typedef float  f4    __attribute__((ext_vector_type(4)));
typedef float  f32x4 __attribute__((ext_vector_type(4)));
typedef short  s16x8 __attribute__((ext_vector_type(8)));
typedef unsigned short u16;
typedef unsigned short u16x4 __attribute__((ext_vector_type(4)));

__device__ __forceinline__ u16 f2bf(float f) {
    unsigned u = __builtin_bit_cast(unsigned, f);
    u += 0x7FFFu + ((u >> 16) & 1u);          // RNE
    return (u16)(u >> 16);
}
__device__ __forceinline__ float bf2f(u16 h) {
    unsigned u = ((unsigned)h) << 16;
    return __builtin_bit_cast(float, u);
}

#define GLOAD_LDS16(g, l) __builtin_amdgcn_global_load_lds( \
    (const __attribute__((address_space(1))) unsigned int*)(g), \
    (__attribute__((address_space(3))) unsigned int*)(l), 16, 0, 0)

#define WAITV4 asm volatile("s_waitcnt vmcnt(4)" ::: "memory")
#define WAITV0 asm volatile("s_waitcnt vmcnt(0)" ::: "memory")
#define LGKMFENCE asm volatile("s_waitcnt lgkmcnt(0)" ::: "memory")
#define SCHB   __builtin_amdgcn_sched_barrier(0)

// ---------------------------------------------------------------------------
// K0a: gate_w f32 -> bf16, layout [o][2048] k-contig. Wf = cols 0..1023,
//      Wm = cols 1024..2047 (accessed with row stride 2048).
// ---------------------------------------------------------------------------
__global__ __launch_bounds__(256) void k_cvt_w(const float* __restrict__ gw,
                                               u16* __restrict__ gwB)
{
    const size_t i = ((size_t)blockIdx.x * 256 + threadIdx.x) * 8;
    f4 v0 = *(const f4*)&gw[i];
    f4 v1 = *(const f4*)&gw[i + 4];
    u16x4 b0 = { f2bf(v0.x), f2bf(v0.y), f2bf(v0.z), f2bf(v0.w) };
    u16x4 b1 = { f2bf(v1.x), f2bf(v1.y), f2bf(v1.z), f2bf(v1.w) };
    *(u16x4*)&gwB[i]     = b0;
    *(u16x4*)&gwB[i + 4] = b1;
}

// ---------------------------------------------------------------------------
// K0b: spatial memory -> {memHi, memLo} [64][1024] bf16 (rows 50..63 zero)
//      and memT [1024][64] bf16 (hi, transposed, zero-padded).
// ---------------------------------------------------------------------------
__global__ __launch_bounds__(256) void k_prep_mem(const float* __restrict__ sm,
                                                  u16* __restrict__ memHi,
                                                  u16* __restrict__ memLo,
                                                  u16* __restrict__ memT)
{
    const int idx = blockIdx.x * 256 + threadIdx.x;   // 16384 total
    const int m  = idx >> 8;
    const int h0 = (idx & 255) * 4;
    f4 v = {0.f, 0.f, 0.f, 0.f};
    if (m < MEMN) v = *(const f4*)&sm[(size_t)m * HD + h0];
    u16x4 hi = { f2bf(v.x), f2bf(v.y), f2bf(v.z), f2bf(v.w) };
    f4 hv = { bf2f(hi.x), bf2f(hi.y), bf2f(hi.z), bf2f(hi.w) };
    f4 lv = v - hv;
    u16x4 lo = { f2bf(lv.x), f2bf(lv.y), f2bf(lv.z), f2bf(lv.w) };
    *(u16x4*)&memHi[(size_t)m * HD + h0] = hi;
    *(u16x4*)&memLo[(size_t)m * HD + h0] = lo;
    memT[(size_t)(h0 + 0) * 64 + m] = hi.x;
    memT[(size_t)(h0 + 1) * 64 + m] = hi.y;
    memT[(size_t)(h0 + 2) * 64 + m] = hi.z;
    memT[(size_t)(h0 + 3) * 64 + m] = hi.w;
}

// ---------------------------------------------------------------------------
// K0c: posM[s][m] = dot(pos[s], M[m])  f32, [200][64], zero-pad m>=50.
// ---------------------------------------------------------------------------
__global__ __launch_bounds__(256) void k_posm(const float* __restrict__ pos,
                                              const float* __restrict__ sm,
                                              float* __restrict__ posM)
{
    __shared__ float red[256];
    const int s = blockIdx.x, m = threadIdx.x & 63, ch = threadIdx.x >> 6;
    float p = 0.f;
    if (m < MEMN) {
        for (int k = ch * 256; k < ch * 256 + 256; k += 4) {
            f4 pv = *(const f4*)&pos[(size_t)s * HD + k];
            f4 mv = *(const f4*)&sm[(size_t)m * HD + k];
            p += pv.x * mv.x + pv.y * mv.y + pv.z * mv.z + pv.w * mv.w;
        }
    }
    red[threadIdx.x] = p;
    __syncthreads();
    if (ch == 0)
        posM[s * 64 + m] = red[m] + red[64 + m] + red[128 + m] + red[192 + m];
}

// ---------------------------------------------------------------------------
// K0d: MWmT[o][m] = (M @ Wm)(m,o) as bf16, [1024][64].  MFMA, 16 blocks.
// ---------------------------------------------------------------------------
__global__ __launch_bounds__(256) void k_mwm(const u16* __restrict__ memHi,
                                             const u16* __restrict__ gwB,
                                             u16* __restrict__ MWmT)
{
    const int tid = threadIdx.x, lane = tid & 63, w = tid >> 6;
    const int fr = lane & 15, fk = (lane >> 4) * 8, jr = (lane >> 4) * 4;
    const int ob = blockIdx.x * 64 + w * 16;       // o-base of this wave
    f32x4 acc[4] = {};
    for (int ks = 0; ks < 32; ++ks) {
        s16x8 b = *(const s16x8*)&gwB[(size_t)(ob + fr) * 2048 + 1024 + ks * 32 + fk];
        #pragma unroll
        for (int mt = 0; mt < 4; ++mt) {
            s16x8 a = *(const s16x8*)&memHi[(size_t)(mt * 16 + fr) * HD + ks * 32 + fk];
            acc[mt] = __builtin_amdgcn_mfma_f32_16x16x32_bf16(a, b, acc[mt], 0, 0, 0);
        }
    }
    #pragma unroll
    for (int mt = 0; mt < 4; ++mt)
        #pragma unroll
        for (int j = 0; j < 4; ++j)
            MWmT[(size_t)(ob + fr) * 64 + mt * 16 + jr + j] = f2bf(acc[mt][j]);
}

// ---------------------------------------------------------------------------
// K1: featsB = bf16(x+pos); sim = x*M^T (hi/lo split MFMA) + posM (f32);
//     softmax -> wBg [51200][64] bf16 (zero-padded). Barrier-free.
// ---------------------------------------------------------------------------
__global__ __launch_bounds__(256) void k_pre(
    const float* __restrict__ x, const float* __restrict__ pos,
    const u16* __restrict__ memHi, const u16* __restrict__ memLo,
    const float* __restrict__ posM,
    u16* __restrict__ featsB, u16* __restrict__ wBg)
{
    __shared__ u16 fHi[64 * PADK];
    __shared__ u16 fLo[64 * PADK];

    const int tid  = threadIdx.x;
    const int r0   = blockIdx.x * 64;
    const int lane = tid & 63, w = tid >> 6;
    const int fr   = lane & 15;
    const int fk   = (lane >> 4) * 8;
    const int jr   = (lane >> 4) * 4;

    const int srow = tid >> 2;            // 16w..16w+15: wave's own rows
    const int scol = (tid & 3) * 4;
    const int prow = (r0 + srow) % SEQL;

    f32x4 acc[4] = {};                    // sim[16 rows][m = n*16 + fr]

    for (int kp = 0; kp < HD; kp += KP) {
        #pragma unroll
        for (int i = 0; i < 8; ++i) {
            const int c = scol + i * 16;
            f4 xv = *(const f4*)&x[(size_t)(r0 + srow) * HD + kp + c];
            f4 pv = *(const f4*)&pos[(size_t)prow * HD + kp + c];
            // featsB = bf16(x + pos)
            f4 fv = xv + pv;
            u16x4 fb = { f2bf(fv.x), f2bf(fv.y), f2bf(fv.z), f2bf(fv.w) };
            *(u16x4*)&featsB[(size_t)(r0 + srow) * HD + kp + c] = fb;
            // hi/lo split of x only (pos handled via posM)
            u16x4 hi = { f2bf(xv.x), f2bf(xv.y), f2bf(xv.z), f2bf(xv.w) };
            f4 hv = { bf2f(hi.x), bf2f(hi.y), bf2f(hi.z), bf2f(hi.w) };
            f4 lv = xv - hv;
            u16x4 lo = { f2bf(lv.x), f2bf(lv.y), f2bf(lv.z), f2bf(lv.w) };
            *(u16x4*)&fHi[srow * PADK + c] = hi;
            *(u16x4*)&fLo[srow * PADK + c] = lo;
        }
        LGKMFENCE;   // wave-local: LDS writes visible to this wave's reads

        #pragma unroll
        for (int ks = 0; ks < KP / 32; ++ks) {
            const int kb = ks * 32 + fk;
            s16x8 aH = *(const s16x8*)&fHi[(16 * w + fr) * PADK + kb];
            s16x8 aL = *(const s16x8*)&fLo[(16 * w + fr) * PADK + kb];
            #pragma unroll
            for (int n = 0; n < 4; ++n) {
                const size_t mb = (size_t)(n * 16 + fr) * HD + kp + kb;
                s16x8 bH = *(const s16x8*)&memHi[mb];
                s16x8 bL = *(const s16x8*)&memLo[mb];
                acc[n] = __builtin_amdgcn_mfma_f32_16x16x32_bf16(aH, bH, acc[n], 0, 0, 0);
                acc[n] = __builtin_amdgcn_mfma_f32_16x16x32_bf16(aH, bL, acc[n], 0, 0, 0);
                acc[n] = __builtin_amdgcn_mfma_f32_16x16x32_bf16(aL, bH, acc[n], 0, 0, 0);
            }
        }
        LGKMFENCE;   // panel reads done before next panel's writes
    }

    // softmax over m (50): sim = acc + posM[s][m] (f32)
    #pragma unroll
    for (int j = 0; j < 4; ++j) {
        const int rg = r0 + 16 * w + jr + j;
        const int rr = rg % SEQL;
        float v[4];
        float mx = -1e30f;
        #pragma unroll
        for (int n = 0; n < 4; ++n) {
            v[n] = acc[n][j] + posM[rr * 64 + n * 16 + fr];
            const int m = n * 16 + fr;
            if (m < MEMN) mx = fmaxf(mx, v[n]);
        }
        #pragma unroll
        for (int d = 1; d < 16; d <<= 1) mx = fmaxf(mx, __shfl_xor(mx, d));
        float e[4], s = 0.f;
        #pragma unroll
        for (int n = 0; n < 4; ++n) {
            const int m = n * 16 + fr;
            e[n] = (m < MEMN) ? __expf(v[n] - mx) : 0.f;
            s += e[n];
        }
        #pragma unroll
        for (int d = 1; d < 16; d <<= 1) s += __shfl_xor(s, d);
        const float inv = 1.f / s;
        #pragma unroll
        for (int n = 0; n < 4; ++n)
            wBg[(size_t)rg * 64 + n * 16 + fr] = f2bf(e[n] * inv); // 0 pad m>=50
    }
}

// ---------------------------------------------------------------------------
// K2: out = featsB + sigmoid(featsB@Wf + w@MWm + b) * (w@M).
//     Main GEMM K=1024 (round-2 winning loop: 128x128, BK=32, 2-buf dist-1,
//     vmcnt(4)) + fused rank-64 MFMA tail for w@MWm (into acc) and w@M (accR).
// ---------------------------------------------------------------------------
__global__ __launch_bounds__(256) void k_gate_out(
    const u16* __restrict__ featsB, const u16* __restrict__ wBg,
    const u16* __restrict__ gwB, const u16* __restrict__ memT,
    const u16* __restrict__ MWmT, const float* __restrict__ gb,
    float* __restrict__ out)
{
    __shared__ u16 As[2][128 * 32];
    __shared__ u16 Bs[2][128 * 32];

    const int tid = threadIdx.x;
    int bid = blockIdx.x;
    bid = (bid & 7) * 400 + (bid >> 3);      // XCD swizzle (3200 % 8 == 0)
    const int mt = bid >> 3, nt = bid & 7;
    const int row0 = mt * 128, col0 = nt * 128;
    const int lane = tid & 63, wave = tid >> 6;
    const int wr = wave >> 1, wc = wave & 1;
    const int fr = lane & 15, fk = (lane >> 4) * 8;

    f32x4 acc[4][4] = {};

    const int sr = tid >> 2;                 // staging row 0..63
    const int sc = (tid & 3) * 8;            // staging col (elements)

    auto stage = [&](int buf, int kt) {
        const int k0 = kt * 32;
        GLOAD_LDS16(featsB + (size_t)(row0 + sr) * HD + k0 + sc,      &As[buf][tid * 8]);
        GLOAD_LDS16(featsB + (size_t)(row0 + 64 + sr) * HD + k0 + sc, &As[buf][2048 + tid * 8]);
        GLOAD_LDS16(gwB + (size_t)(col0 + sr) * 2048 + k0 + sc,      &Bs[buf][tid * 8]);
        GLOAD_LDS16(gwB + (size_t)(col0 + 64 + sr) * 2048 + k0 + sc, &Bs[buf][2048 + tid * 8]);
    };

    stage(0, 0);
    int cur = 0;

    for (int kt = 0; kt < 32; ++kt) {
        if (kt < 31) {
            stage(cur ^ 1, kt + 1);
            WAITV4;                          // cur's 4 loads done
        } else {
            WAITV0;
        }
        __builtin_amdgcn_s_barrier();
        SCHB;

        s16x8 aF[4], bF[4];
        #pragma unroll
        for (int m = 0; m < 4; ++m)
            aF[m] = *(const s16x8*)&As[cur][(wr * 64 + m * 16 + fr) * 32 + fk];
        #pragma unroll
        for (int n = 0; n < 4; ++n)
            bF[n] = *(const s16x8*)&Bs[cur][(wc * 64 + n * 16 + fr) * 32 + fk];
        #pragma unroll
        for (int m = 0; m < 4; ++m)
            #pragma unroll
            for (int n = 0; n < 4; ++n)
                acc[m][n] = __builtin_amdgcn_mfma_f32_16x16x32_bf16(
                    aF[m], bF[n], acc[m][n], 0, 0, 0);

        SCHB;
        __builtin_amdgcn_s_barrier();
        cur ^= 1;
    }

    // rank-64 tail: acc += w @ MWm (gate term), accR = w @ M (mem_read, f32)
    f32x4 accR[4][4] = {};
    #pragma unroll
    for (int ks = 0; ks < 2; ++ks) {
        s16x8 a2[4], bW[4], bT[4];
        #pragma unroll
        for (int m = 0; m < 4; ++m)
            a2[m] = *(const s16x8*)&wBg[(size_t)(row0 + wr * 64 + m * 16 + fr) * 64 + ks * 32 + fk];
        #pragma unroll
        for (int n = 0; n < 4; ++n) {
            const size_t c = (size_t)(col0 + wc * 64 + n * 16 + fr) * 64 + ks * 32 + fk;
            bW[n] = *(const s16x8*)&MWmT[c];
            bT[n] = *(const s16x8*)&memT[c];
        }
        #pragma unroll
        for (int m = 0; m < 4; ++m)
            #pragma unroll
            for (int n = 0; n < 4; ++n) {
                acc[m][n]  = __builtin_amdgcn_mfma_f32_16x16x32_bf16(
                    a2[m], bW[n], acc[m][n], 0, 0, 0);
                accR[m][n] = __builtin_amdgcn_mfma_f32_16x16x32_bf16(
                    a2[m], bT[n], accR[m][n], 0, 0, 0);
            }
    }

    // epilogue: out = feats + sigmoid(acc + b) * accR
    #pragma unroll
    for (int m = 0; m < 4; ++m) {
        #pragma unroll
        for (int n = 0; n < 4; ++n) {
            const int crow = row0 + wr * 64 + m * 16 + (lane >> 4) * 4;
            const int ccol = col0 + wc * 64 + n * 16 + fr;
            const float bias = gb[ccol];
            #pragma unroll
            for (int j = 0; j < 4; ++j) {
                const size_t idx = (size_t)(crow + j) * HD + ccol;
                const float fe = bf2f(featsB[idx]);
                const float pre = acc[m][n][j] + bias;
                const float g = 1.0f / (1.0f + __expf(-pre));
                out[idx] = fe + g * accR[m][n][j];
            }
        }
    }
}

// ---------------------------------------------------------------------------
extern "C" void kernel_launch(void* const* d_in, const int* in_sizes, int n_in,
                              void* d_out, int out_size, void* d_ws, size_t ws_size,
                              hipStream_t stream)
{
    const float* x   = (const float*)d_in[0];
    const float* sm  = (const float*)d_in[1];
    const float* pos = (const float*)d_in[2];
    const float* gw  = (const float*)d_in[3];
    const float* gb  = (const float*)d_in[4];
    float* out = (float*)d_out;

    u16* featsB = (u16*)d_ws;                          // 51200*1024
    u16* gwB    = featsB + (size_t)RTOT * HD;          // 1024*2048
    u16* wBg    = gwB + (size_t)HD * 2048;             // 51200*64
    u16* memHi  = wBg + (size_t)RTOT * 64;             // 64*1024
    u16* memLo  = memHi + 64 * HD;                     // 64*1024
    u16* memT   = memLo + 64 * HD;                     // 1024*64
    u16* MWmT   = memT + (size_t)HD * 64;              // 1024*64
    float* posM = (float*)(MWmT + (size_t)HD * 64);    // 200*64 f32

    k_cvt_w<<<dim3(1024), dim3(256), 0, stream>>>(gw, gwB);
    k_prep_mem<<<dim3(64), dim3(256), 0, stream>>>(sm, memHi, memLo, memT);
    k_posm<<<dim3(SEQL), dim3(256), 0, stream>>>(pos, sm, posM);
    k_mwm<<<dim3(16), dim3(256), 0, stream>>>(memHi, gwB, MWmT);
    k_pre<<<dim3(RTOT / 64), dim3(256), 0, stream>>>(x, pos, memHi, memLo, posM,
                                                     featsB, wBg);
    k_gate_out<<<dim3(3200), dim3(256), 0, stream>>>(featsB, wBg, gwB, memT,
                                                     MWmT, gb, out);
}

// Round 7
// 494.220 us; speedup vs baseline: 1.3602x; 1.2427x over previous
//
#include <hip/hip_runtime.h>
#include <cstdint>
#include <cstddef>

#define HD   1024
#define SEQL 200
#define MEMN 50
#define RTOT 51200   // 256 * 200
#define KP   128
#define PADK 136     // KP + 8 bf16 pad -> LDS row stride 272B (2-way, free)

typedef float  f4    __attribute__((ext_vector_type(4)));
typedef float  f32x4 __attribute__((ext_vector_type(4)));
typedef short  s16x8 __attribute__((ext_vector_type(8)));
typedef unsigned short u16;
typedef unsigned short u16x4 __attribute__((ext_vector_type(4)));

__device__ __forceinline__ u16 f2bf(float f) {
    unsigned u = __builtin_bit_cast(unsigned, f);
    u += 0x7FFFu + ((u >> 16) & 1u);          // RNE
    return (u16)(u >> 16);
}
__device__ __forceinline__ float bf2f(u16 h) {
    unsigned u = ((unsigned)h) << 16;
    return __builtin_bit_cast(float, u);
}

#define GLOAD_LDS16(g, l) __builtin_amdgcn_global_load_lds( \
    (const __attribute__((address_space(1))) unsigned int*)(g), \
    (__attribute__((address_space(3))) unsigned int*)(l), 16, 0, 0)

#define WAITV4 asm volatile("s_waitcnt vmcnt(4)" ::: "memory")
#define WAITV0 asm volatile("s_waitcnt vmcnt(0)" ::: "memory")
#define LGKMFENCE asm volatile("s_waitcnt lgkmcnt(0)" ::: "memory")
#define SCHB   __builtin_amdgcn_sched_barrier(0)

// ---------------------------------------------------------------------------
// K0a: gate_w f32 -> bf16, layout [o][2048] k-contig. Wf = cols 0..1023,
//      Wm = cols 1024..2047 (accessed with row stride 2048).
// ---------------------------------------------------------------------------
__global__ __launch_bounds__(256) void k_cvt_w(const float* __restrict__ gw,
                                               u16* __restrict__ gwB)
{
    const size_t i = ((size_t)blockIdx.x * 256 + threadIdx.x) * 8;
    f4 v0 = *(const f4*)&gw[i];
    f4 v1 = *(const f4*)&gw[i + 4];
    u16x4 b0 = { f2bf(v0.x), f2bf(v0.y), f2bf(v0.z), f2bf(v0.w) };
    u16x4 b1 = { f2bf(v1.x), f2bf(v1.y), f2bf(v1.z), f2bf(v1.w) };
    *(u16x4*)&gwB[i]     = b0;
    *(u16x4*)&gwB[i + 4] = b1;
}

// ---------------------------------------------------------------------------
// K0b: spatial memory -> {memHi, memLo} [64][1024] bf16 (rows 50..63 zero)
//      and memT [1024][64] bf16 (hi, transposed, zero-padded).
// ---------------------------------------------------------------------------
__global__ __launch_bounds__(256) void k_prep_mem(const float* __restrict__ sm,
                                                  u16* __restrict__ memHi,
                                                  u16* __restrict__ memLo,
                                                  u16* __restrict__ memT)
{
    const int idx = blockIdx.x * 256 + threadIdx.x;   // 16384 total
    const int m  = idx >> 8;
    const int h0 = (idx & 255) * 4;
    f4 v = {0.f, 0.f, 0.f, 0.f};
    if (m < MEMN) v = *(const f4*)&sm[(size_t)m * HD + h0];
    u16x4 hi = { f2bf(v.x), f2bf(v.y), f2bf(v.z), f2bf(v.w) };
    f4 hv = { bf2f(hi.x), bf2f(hi.y), bf2f(hi.z), bf2f(hi.w) };
    f4 lv = v - hv;
    u16x4 lo = { f2bf(lv.x), f2bf(lv.y), f2bf(lv.z), f2bf(lv.w) };
    *(u16x4*)&memHi[(size_t)m * HD + h0] = hi;
    *(u16x4*)&memLo[(size_t)m * HD + h0] = lo;
    memT[(size_t)(h0 + 0) * 64 + m] = hi.x;
    memT[(size_t)(h0 + 1) * 64 + m] = hi.y;
    memT[(size_t)(h0 + 2) * 64 + m] = hi.z;
    memT[(size_t)(h0 + 3) * 64 + m] = hi.w;
}

// ---------------------------------------------------------------------------
// K0c: posM[s][m] = dot(pos[s], M[m])  f32, [200][64], zero-pad m>=50.
// ---------------------------------------------------------------------------
__global__ __launch_bounds__(256) void k_posm(const float* __restrict__ pos,
                                              const float* __restrict__ sm,
                                              float* __restrict__ posM)
{
    __shared__ float red[256];
    const int s = blockIdx.x, m = threadIdx.x & 63, ch = threadIdx.x >> 6;
    float p = 0.f;
    if (m < MEMN) {
        for (int k = ch * 256; k < ch * 256 + 256; k += 4) {
            f4 pv = *(const f4*)&pos[(size_t)s * HD + k];
            f4 mv = *(const f4*)&sm[(size_t)m * HD + k];
            p += pv.x * mv.x + pv.y * mv.y + pv.z * mv.z + pv.w * mv.w;
        }
    }
    red[threadIdx.x] = p;
    __syncthreads();
    if (ch == 0)
        posM[s * 64 + m] = red[m] + red[64 + m] + red[128 + m] + red[192 + m];
}

// ---------------------------------------------------------------------------
// K0d: MWmT[o][m] = (M @ Wm)(m,o) as bf16, [1024][64].  MFMA, 16 blocks.
// ---------------------------------------------------------------------------
__global__ __launch_bounds__(256) void k_mwm(const u16* __restrict__ memHi,
                                             const u16* __restrict__ gwB,
                                             u16* __restrict__ MWmT)
{
    const int tid = threadIdx.x, lane = tid & 63, w = tid >> 6;
    const int fr = lane & 15, fk = (lane >> 4) * 8, jr = (lane >> 4) * 4;
    const int ob = blockIdx.x * 64 + w * 16;       // o-base of this wave
    f32x4 acc[4] = {};
    for (int ks = 0; ks < 32; ++ks) {
        s16x8 b = *(const s16x8*)&gwB[(size_t)(ob + fr) * 2048 + 1024 + ks * 32 + fk];
        #pragma unroll
        for (int mt = 0; mt < 4; ++mt) {
            s16x8 a = *(const s16x8*)&memHi[(size_t)(mt * 16 + fr) * HD + ks * 32 + fk];
            acc[mt] = __builtin_amdgcn_mfma_f32_16x16x32_bf16(a, b, acc[mt], 0, 0, 0);
        }
    }
    #pragma unroll
    for (int mt = 0; mt < 4; ++mt)
        #pragma unroll
        for (int j = 0; j < 4; ++j)
            MWmT[(size_t)(ob + fr) * 64 + mt * 16 + jr + j] = f2bf(acc[mt][j]);
}

// ---------------------------------------------------------------------------
// K1: featsB = bf16(x+pos); sim = x*M^T (hi/lo split MFMA) + posM (f32);
//     softmax -> wBg [51200][64] bf16 (zero-padded). Barrier-free;
//     register-prefetch: panel p+1's x/pos loads issue before panel p's MFMA.
// ---------------------------------------------------------------------------
__global__ __launch_bounds__(256) void k_pre(
    const float* __restrict__ x, const float* __restrict__ pos,
    const u16* __restrict__ memHi, const u16* __restrict__ memLo,
    const float* __restrict__ posM,
    u16* __restrict__ featsB, u16* __restrict__ wBg)
{
    __shared__ u16 fHi[64 * PADK];
    __shared__ u16 fLo[64 * PADK];

    const int tid  = threadIdx.x;
    const int r0   = blockIdx.x * 64;
    const int lane = tid & 63, w = tid >> 6;
    const int fr   = lane & 15;
    const int fk   = (lane >> 4) * 8;
    const int jr   = (lane >> 4) * 4;

    const int srow = tid >> 2;            // 16w..16w+15: wave's own rows
    const int scol = (tid & 3) * 4;
    const int prow = (r0 + srow) % SEQL;

    const float* xrow = &x[(size_t)(r0 + srow) * HD];
    const float* prow_p = &pos[(size_t)prow * HD];

    f4 xv[8], pv[8];
    #pragma unroll
    for (int i = 0; i < 8; ++i) {
        const int c = scol + i * 16;
        xv[i] = *(const f4*)&xrow[c];
        pv[i] = *(const f4*)&prow_p[c];
    }

    f32x4 acc[4] = {};                    // sim[16 rows][m = n*16 + fr]

    for (int kp = 0; kp < HD; kp += KP) {
        // ---- convert current panel regs -> LDS hi/lo + featsB store ----
        #pragma unroll
        for (int i = 0; i < 8; ++i) {
            const int c = scol + i * 16;
            f4 fv = xv[i] + pv[i];
            u16x4 fb = { f2bf(fv.x), f2bf(fv.y), f2bf(fv.z), f2bf(fv.w) };
            *(u16x4*)&featsB[(size_t)(r0 + srow) * HD + kp + c] = fb;
            u16x4 hi = { f2bf(xv[i].x), f2bf(xv[i].y), f2bf(xv[i].z), f2bf(xv[i].w) };
            f4 hv = { bf2f(hi.x), bf2f(hi.y), bf2f(hi.z), bf2f(hi.w) };
            f4 lv = xv[i] - hv;
            u16x4 lo = { f2bf(lv.x), f2bf(lv.y), f2bf(lv.z), f2bf(lv.w) };
            *(u16x4*)&fHi[srow * PADK + c] = hi;
            *(u16x4*)&fLo[srow * PADK + c] = lo;
        }
        LGKMFENCE;   // wave-local: LDS writes visible to this wave's reads

        // ---- prefetch next panel into regs (hides HBM under MFMA below) ----
        if (kp + KP < HD) {
            #pragma unroll
            for (int i = 0; i < 8; ++i) {
                const int c = kp + KP + scol + i * 16;
                xv[i] = *(const f4*)&xrow[c];
                pv[i] = *(const f4*)&prow_p[c];
            }
        }

        // ---- sim MFMA: 3 split-passes, B-frags straight from L2 ----
        #pragma unroll
        for (int ks = 0; ks < KP / 32; ++ks) {
            const int kb = ks * 32 + fk;
            s16x8 aH = *(const s16x8*)&fHi[(16 * w + fr) * PADK + kb];
            s16x8 aL = *(const s16x8*)&fLo[(16 * w + fr) * PADK + kb];
            #pragma unroll
            for (int n = 0; n < 4; ++n) {
                const size_t mb = (size_t)(n * 16 + fr) * HD + kp + kb;
                s16x8 bH = *(const s16x8*)&memHi[mb];
                s16x8 bL = *(const s16x8*)&memLo[mb];
                acc[n] = __builtin_amdgcn_mfma_f32_16x16x32_bf16(aH, bH, acc[n], 0, 0, 0);
                acc[n] = __builtin_amdgcn_mfma_f32_16x16x32_bf16(aH, bL, acc[n], 0, 0, 0);
                acc[n] = __builtin_amdgcn_mfma_f32_16x16x32_bf16(aL, bH, acc[n], 0, 0, 0);
            }
        }
        LGKMFENCE;   // panel reads done before next panel's writes
    }

    // softmax over m (50): sim = acc + posM[s][m] (f32)
    #pragma unroll
    for (int j = 0; j < 4; ++j) {
        const int rg = r0 + 16 * w + jr + j;
        const int rr = rg % SEQL;
        float v[4];
        float mx = -1e30f;
        #pragma unroll
        for (int n = 0; n < 4; ++n) {
            v[n] = acc[n][j] + posM[rr * 64 + n * 16 + fr];
            const int m = n * 16 + fr;
            if (m < MEMN) mx = fmaxf(mx, v[n]);
        }
        #pragma unroll
        for (int d = 1; d < 16; d <<= 1) mx = fmaxf(mx, __shfl_xor(mx, d));
        float e[4], s = 0.f;
        #pragma unroll
        for (int n = 0; n < 4; ++n) {
            const int m = n * 16 + fr;
            e[n] = (m < MEMN) ? __expf(v[n] - mx) : 0.f;
            s += e[n];
        }
        #pragma unroll
        for (int d = 1; d < 16; d <<= 1) s += __shfl_xor(s, d);
        const float inv = 1.f / s;
        #pragma unroll
        for (int n = 0; n < 4; ++n)
            wBg[(size_t)rg * 64 + n * 16 + fr] = f2bf(e[n] * inv); // 0 pad m>=50
    }
}

// ---------------------------------------------------------------------------
// K2: out = featsB + sigmoid([featsB|w]@[Wf;MWm] + b) * (w@M).
//     Main GEMM K=1088 (34 tiles: 32 of featsB@Wf + 2 of w@MWm), round-2 loop
//     (128x128, BK=32, 2-buf dist-1, vmcnt(4)). accR = w@M computed per-(m,n)
//     in the epilogue (one transient f32x4 -> no accumulator doubling).
// ---------------------------------------------------------------------------
__global__ __launch_bounds__(256) void k_gate_out(
    const u16* __restrict__ featsB, const u16* __restrict__ wBg,
    const u16* __restrict__ gwB, const u16* __restrict__ memT,
    const u16* __restrict__ MWmT, const float* __restrict__ gb,
    float* __restrict__ out)
{
    __shared__ u16 As[2][128 * 32];
    __shared__ u16 Bs[2][128 * 32];

    const int tid = threadIdx.x;
    int bid = blockIdx.x;
    bid = (bid & 7) * 400 + (bid >> 3);      // XCD swizzle (3200 % 8 == 0)
    const int mt = bid >> 3, nt = bid & 7;
    const int row0 = mt * 128, col0 = nt * 128;
    const int lane = tid & 63, wave = tid >> 6;
    const int wr = wave >> 1, wc = wave & 1;
    const int fr = lane & 15, fk = (lane >> 4) * 8;

    f32x4 acc[4][4] = {};

    const int sr = tid >> 2;                 // staging row 0..63
    const int sc = (tid & 3) * 8;            // staging col (elements)

    auto stage = [&](int buf, int kt) {
        if (kt < 32) {
            const int k0 = kt * 32;
            GLOAD_LDS16(featsB + (size_t)(row0 + sr) * HD + k0 + sc,      &As[buf][tid * 8]);
            GLOAD_LDS16(featsB + (size_t)(row0 + 64 + sr) * HD + k0 + sc, &As[buf][2048 + tid * 8]);
            GLOAD_LDS16(gwB + (size_t)(col0 + sr) * 2048 + k0 + sc,      &Bs[buf][tid * 8]);
            GLOAD_LDS16(gwB + (size_t)(col0 + 64 + sr) * 2048 + k0 + sc, &Bs[buf][2048 + tid * 8]);
        } else {
            const int k0 = (kt - 32) * 32;
            GLOAD_LDS16(wBg + (size_t)(row0 + sr) * 64 + k0 + sc,      &As[buf][tid * 8]);
            GLOAD_LDS16(wBg + (size_t)(row0 + 64 + sr) * 64 + k0 + sc, &As[buf][2048 + tid * 8]);
            GLOAD_LDS16(MWmT + (size_t)(col0 + sr) * 64 + k0 + sc,      &Bs[buf][tid * 8]);
            GLOAD_LDS16(MWmT + (size_t)(col0 + 64 + sr) * 64 + k0 + sc, &Bs[buf][2048 + tid * 8]);
        }
    };

    stage(0, 0);
    int cur = 0;

    for (int kt = 0; kt < 34; ++kt) {
        if (kt < 33) {
            stage(cur ^ 1, kt + 1);
            WAITV4;                          // cur's 4 loads done
        } else {
            WAITV0;
        }
        __builtin_amdgcn_s_barrier();
        SCHB;

        s16x8 aF[4], bF[4];
        #pragma unroll
        for (int m = 0; m < 4; ++m)
            aF[m] = *(const s16x8*)&As[cur][(wr * 64 + m * 16 + fr) * 32 + fk];
        #pragma unroll
        for (int n = 0; n < 4; ++n)
            bF[n] = *(const s16x8*)&Bs[cur][(wc * 64 + n * 16 + fr) * 32 + fk];
        #pragma unroll
        for (int m = 0; m < 4; ++m)
            #pragma unroll
            for (int n = 0; n < 4; ++n)
                acc[m][n] = __builtin_amdgcn_mfma_f32_16x16x32_bf16(
                    aF[m], bF[n], acc[m][n], 0, 0, 0);

        SCHB;
        __builtin_amdgcn_s_barrier();
        cur ^= 1;
    }

    // epilogue: accR = w@M per (m,n); out = feats + sigmoid(acc+b)*accR
    #pragma unroll
    for (int m = 0; m < 4; ++m) {
        const size_t ab = (size_t)(row0 + wr * 64 + m * 16 + fr) * 64 + fk;
        s16x8 a2_0 = *(const s16x8*)&wBg[ab];
        s16x8 a2_1 = *(const s16x8*)&wBg[ab + 32];
        #pragma unroll
        for (int n = 0; n < 4; ++n) {
            const size_t cb = (size_t)(col0 + wc * 64 + n * 16 + fr) * 64 + fk;
            s16x8 bT0 = *(const s16x8*)&memT[cb];
            s16x8 bT1 = *(const s16x8*)&memT[cb + 32];
            f32x4 accR = {};
            accR = __builtin_amdgcn_mfma_f32_16x16x32_bf16(a2_0, bT0, accR, 0, 0, 0);
            accR = __builtin_amdgcn_mfma_f32_16x16x32_bf16(a2_1, bT1, accR, 0, 0, 0);

            const int crow = row0 + wr * 64 + m * 16 + (lane >> 4) * 4;
            const int ccol = col0 + wc * 64 + n * 16 + fr;
            const float bias = gb[ccol];
            #pragma unroll
            for (int j = 0; j < 4; ++j) {
                const size_t idx = (size_t)(crow + j) * HD + ccol;
                const float fe = bf2f(featsB[idx]);
                const float pre = acc[m][n][j] + bias;
                const float g = 1.0f / (1.0f + __expf(-pre));
                out[idx] = fe + g * accR[j];
            }
        }
    }
}

// ---------------------------------------------------------------------------
extern "C" void kernel_launch(void* const* d_in, const int* in_sizes, int n_in,
                              void* d_out, int out_size, void* d_ws, size_t ws_size,
                              hipStream_t stream)
{
    const float* x   = (const float*)d_in[0];
    const float* sm  = (const float*)d_in[1];
    const float* pos = (const float*)d_in[2];
    const float* gw  = (const float*)d_in[3];
    const float* gb  = (const float*)d_in[4];
    float* out = (float*)d_out;

    u16* featsB = (u16*)d_ws;                          // 51200*1024
    u16* gwB    = featsB + (size_t)RTOT * HD;          // 1024*2048
    u16* wBg    = gwB + (size_t)HD * 2048;             // 51200*64
    u16* memHi  = wBg + (size_t)RTOT * 64;             // 64*1024
    u16* memLo  = memHi + 64 * HD;                     // 64*1024
    u16* memT   = memLo + 64 * HD;                     // 1024*64
    u16* MWmT   = memT + (size_t)HD * 64;              // 1024*64
    float* posM = (float*)(MWmT + (size_t)HD * 64);    // 200*64 f32

    k_cvt_w<<<dim3(1024), dim3(256), 0, stream>>>(gw, gwB);
    k_prep_mem<<<dim3(64), dim3(256), 0, stream>>>(sm, memHi, memLo, memT);
    k_posm<<<dim3(SEQL), dim3(256), 0, stream>>>(pos, sm, posM);
    k_mwm<<<dim3(16), dim3(256), 0, stream>>>(memHi, gwB, MWmT);
    k_pre<<<dim3(RTOT / 64), dim3(256), 0, stream>>>(x, pos, memHi, memLo, posM,
                                                     featsB, wBg);
    k_gate_out<<<dim3(3200), dim3(256), 0, stream>>>(featsB, wBg, gwB, memT,
                                                     MWmT, gb, out);
}